// Round 6
// baseline (291.376 us; speedup 1.0000x reference)
//
#include <hip/hip_runtime.h>

#define NS 10
#define PACKB 2592  // (2*2*256*576 + 2*64*576) / 256

typedef __attribute__((ext_vector_type(8))) short bf16x8;
typedef __attribute__((ext_vector_type(4))) float f32x4;

__device__ __forceinline__ float bf2f(unsigned short u) {
  union { unsigned int i; float f; } x;
  x.i = ((unsigned int)u) << 16;
  return x.f;
}
__device__ __forceinline__ unsigned short f2bf(float f) {
  union { float f; unsigned int i; } x; x.f = f;
  unsigned int r = x.i + 0x7FFFu + ((x.i >> 16) & 1u);
  return (unsigned short)(r >> 16);
}
__device__ __forceinline__ unsigned pk2(float a, float b) {
  return (unsigned)f2bf(a) | ((unsigned)f2bf(b) << 16);
}

// ===== gprep: weight pack + gathers; dual jobs write direct rows AND mean ===
struct GJob {
  const float* table; const int* idx;
  unsigned short* out; unsigned short* out2;   // out2: direct rows (dual jobs)
  int M, D4, ns, ostride, ostride2, blk0; float inv;
};
struct GJobs { GJob j[10]; };

__global__ __launch_bounds__(256) void gprep_k(
    GJobs js, int njobs,
    const float* __restrict__ Wself, const float* __restrict__ Wneigh,
    const float* __restrict__ Wedg, const float* __restrict__ Wec,
    unsigned short* __restrict__ wt1, unsigned short* __restrict__ wte) {
  int b = blockIdx.x;
  if (b < PACKB) {
    int t = b * 256 + threadIdx.x;
    const int total1 = 2 * 2 * 256 * 576;
    if (t < total1) {
      int g = t / 147456, r = t - g * 147456;
      int n = r / 576, k = r - n * 576;
      float v;
      if (k < 256) v = Wself[(long)g * 65536 + k * 256 + n];
      else if (k < 512) v = Wneigh[(long)g * 65536 + (k - 256) * 256 + n];
      else v = Wedg[(long)g * 16384 + (k - 512) * 256 + n];
      wt1[t] = f2bf(v);
    } else {
      int t2 = t - total1;  // < 2*64*576
      int mp = t2 / 36864, r = t2 - mp * 36864;
      int n = r / 576, k = r - n * 576;
      wte[t2] = f2bf(Wec[(long)(mp * 2) * 36864 + k * 64 + n]);
    }
    return;
  }
  b -= PACKB;
  int ji = 0;
  for (int k = 1; k < njobs; ++k) if (b >= js.j[k].blk0) ji = k;
  GJob jb = js.j[ji];
  int t = (b - jb.blk0) * 256 + threadIdx.x;
  int m = t / jb.D4, d4 = t - m * jb.D4;
  long D = (long)jb.D4 * 4;
  float ax = 0.f, ay = 0.f, az = 0.f, aw = 0.f;
  if (jb.ns == NS) {
    int ridx[NS];
#pragma unroll
    for (int s = 0; s < NS; ++s) ridx[s] = jb.idx[(long)m * NS + s];
    float4 vv[NS];
#pragma unroll
    for (int s = 0; s < NS; ++s)
      vv[s] = *(const float4*)(jb.table + (long)ridx[s] * D + d4 * 4);
#pragma unroll
    for (int s = 0; s < NS; ++s) {
      ax += vv[s].x; ay += vv[s].y; az += vv[s].z; aw += vv[s].w;
    }
    if (jb.out2) {  // dual: also emit the 10 direct rows (scale 1.0)
#pragma unroll
      for (int s = 0; s < NS; ++s) {
        uint2 o2; o2.x = pk2(vv[s].x, vv[s].y); o2.y = pk2(vv[s].z, vv[s].w);
        *(uint2*)(jb.out2 + (long)(m * NS + s) * jb.ostride2 + d4 * 4) = o2;
      }
    }
  } else {
    long r = (long)jb.idx[m];
    float4 v = *(const float4*)(jb.table + r * D + d4 * 4);
    ax = v.x; ay = v.y; az = v.z; aw = v.w;
  }
  uint2 o; o.x = pk2(ax * jb.inv, ay * jb.inv); o.y = pk2(az * jb.inv, aw * jb.inv);
  *(uint2*)(jb.out + (long)m * jb.ostride + d4 * 4) = o;
}

// ===== GEMM1: h01 = relu(A1b @ WT1[mp][0]); BM=64 BN=64 ====================
// LDS-free: every MFMA fragment is 16B-contiguous in global; load direct to
// regs. No barriers in the K-loop -> compiler pipelines freely. 704 tiles.
__global__ __launch_bounds__(256) void gemm1_k(
    const unsigned short* __restrict__ A, const unsigned short* __restrict__ wt1,
    unsigned short* __restrict__ C, unsigned short* __restrict__ A3) {
  int tid = threadIdx.x, tile = blockIdx.x;
  int mp = tile & 1, t2 = tile >> 1;
  int n0 = (t2 & 3) * 64, m0 = (t2 >> 2) * 64;
  const unsigned short* Ap = A + (long)mp * (5632L * 576) + (long)m0 * 576;
  const unsigned short* Bp = wt1 + (long)mp * 2 * 147456 + (long)n0 * 576;

  int wave = tid >> 6, lane = tid & 63;
  int wm = wave >> 1, wn = wave & 1;
  int quad = lane >> 4, r16 = lane & 15;

  const unsigned short *pa[2], *pb[2];
#pragma unroll
  for (int i = 0; i < 2; ++i)
    pa[i] = Ap + (long)(wm * 32 + i * 16 + r16) * 576 + quad * 8;
#pragma unroll
  for (int j = 0; j < 2; ++j)
    pb[j] = Bp + (long)(wn * 32 + j * 16 + r16) * 576 + quad * 8;

  f32x4 acc[2][2];
#pragma unroll
  for (int i = 0; i < 2; ++i)
#pragma unroll
    for (int j = 0; j < 2; ++j) acc[i][j] = (f32x4){0.f, 0.f, 0.f, 0.f};

#pragma unroll
  for (int it = 0; it < 18; ++it) {
    bf16x8 av[2], bv[2];
#pragma unroll
    for (int i = 0; i < 2; ++i) av[i] = *(const bf16x8*)(pa[i] + it * 32);
#pragma unroll
    for (int j = 0; j < 2; ++j) bv[j] = *(const bf16x8*)(pb[j] + it * 32);
#pragma unroll
    for (int i = 0; i < 2; ++i)
#pragma unroll
      for (int j = 0; j < 2; ++j)
        acc[i][j] = __builtin_amdgcn_mfma_f32_16x16x32_bf16(av[i], bv[j], acc[i][j], 0, 0, 0);
  }
#pragma unroll
  for (int i = 0; i < 2; ++i)
#pragma unroll
    for (int j = 0; j < 2; ++j)
#pragma unroll
      for (int r = 0; r < 4; ++r) {
        int rr = m0 + wm * 32 + i * 16 + quad * 4 + r;
        int cc = n0 + wn * 32 + j * 16 + r16;
        unsigned short u = f2bf(fmaxf(acc[i][j][r], 0.f));
        C[(long)mp * (5632L * 256) + (long)rr * 256 + cc] = u;
        if (rr < 512)
          A3[(long)mp * (512L * 576) + (long)rr * 576 + cc] = u;
      }
}

// ===== P3: edge GEMM (160 tiles, LDS-free) || h1-means (128 block-jobs) ====
__device__ void edge_tile(int tile, const unsigned short* h01, const unsigned short* eg0,
                          const unsigned short* wte, const float* bec,
                          unsigned short* enew, int tid) {
  int mp = tile & 1;
  int m0 = (tile >> 1) * 64;
  const unsigned short* h0 = h01 + (long)mp * (5632L * 256);
  const unsigned short* h1 = h0 + 512 * 256;
  const unsigned short* eg = eg0 + (long)mp * (5120L * 64);
  const unsigned short* Bp = wte + (long)mp * 36864;

  int wave = tid >> 6, lane = tid & 63;
  int wm = wave >> 1, wn = wave & 1;
  int quad = lane >> 4, r16 = lane & 15;

  const unsigned short *pa0[2], *pa1[2], *pa2[2], *pb[2];
#pragma unroll
  for (int i = 0; i < 2; ++i) {
    int gr = m0 + wm * 32 + i * 16 + r16;
    int ar0 = gr / 10;
    pa0[i] = h0 + (long)ar0 * 256 + quad * 8;   // src (h0 repeated x10)
    pa1[i] = h1 + (long)gr * 256 + quad * 8;    // dst
    pa2[i] = eg + (long)gr * 64 + quad * 8;     // edge emb
  }
#pragma unroll
  for (int j = 0; j < 2; ++j)
    pb[j] = Bp + (long)(wn * 32 + j * 16 + r16) * 576 + quad * 8;

  f32x4 acc[2][2];
#pragma unroll
  for (int i = 0; i < 2; ++i)
#pragma unroll
    for (int j = 0; j < 2; ++j) acc[i][j] = (f32x4){0.f, 0.f, 0.f, 0.f};

#pragma unroll
  for (int it = 0; it < 8; ++it) {  // k segment 1: src
    bf16x8 av[2], bv[2];
#pragma unroll
    for (int i = 0; i < 2; ++i) av[i] = *(const bf16x8*)(pa0[i] + it * 32);
#pragma unroll
    for (int j = 0; j < 2; ++j) bv[j] = *(const bf16x8*)(pb[j] + it * 32);
#pragma unroll
    for (int i = 0; i < 2; ++i)
#pragma unroll
      for (int j = 0; j < 2; ++j)
        acc[i][j] = __builtin_amdgcn_mfma_f32_16x16x32_bf16(av[i], bv[j], acc[i][j], 0, 0, 0);
  }
#pragma unroll
  for (int it = 0; it < 8; ++it) {  // k segment 2: dst
    bf16x8 av[2], bv[2];
#pragma unroll
    for (int i = 0; i < 2; ++i) av[i] = *(const bf16x8*)(pa1[i] + it * 32);
#pragma unroll
    for (int j = 0; j < 2; ++j) bv[j] = *(const bf16x8*)(pb[j] + (8 + it) * 32);
#pragma unroll
    for (int i = 0; i < 2; ++i)
#pragma unroll
      for (int j = 0; j < 2; ++j)
        acc[i][j] = __builtin_amdgcn_mfma_f32_16x16x32_bf16(av[i], bv[j], acc[i][j], 0, 0, 0);
  }
#pragma unroll
  for (int it = 0; it < 2; ++it) {  // k segment 3: edge emb
    bf16x8 av[2], bv[2];
#pragma unroll
    for (int i = 0; i < 2; ++i) av[i] = *(const bf16x8*)(pa2[i] + it * 32);
#pragma unroll
    for (int j = 0; j < 2; ++j) bv[j] = *(const bf16x8*)(pb[j] + (16 + it) * 32);
#pragma unroll
    for (int i = 0; i < 2; ++i)
#pragma unroll
      for (int j = 0; j < 2; ++j)
        acc[i][j] = __builtin_amdgcn_mfma_f32_16x16x32_bf16(av[i], bv[j], acc[i][j], 0, 0, 0);
  }
#pragma unroll
  for (int i = 0; i < 2; ++i)
#pragma unroll
    for (int j = 0; j < 2; ++j)
#pragma unroll
      for (int r = 0; r < 4; ++r) {
        int rr = m0 + wm * 32 + i * 16 + quad * 4 + r;
        int cc = wn * 32 + j * 16 + r16;
        float v = tanhf(acc[i][j][r] + bec[mp * 128 + cc]);
        enew[(long)mp * (5120L * 64) + (long)rr * 64 + cc] = f2bf(v);
      }
}

__device__ __forceinline__ void h1mean_item(int t, const unsigned short* h01,
                                            unsigned short* A3) {
  // t in [0, 32768): mp = t>>14, m = (t&16383)>>5, d8 = t&31
  int mp = t >> 14, t14 = t & 16383;
  int m = t14 >> 5, d8 = t14 & 31;
  const unsigned short* h1 = h01 + (long)mp * (5632L * 256) + 512 * 256;
  float s[8];
#pragma unroll
  for (int x = 0; x < 8; ++x) s[x] = 0.f;
#pragma unroll
  for (int ss = 0; ss < NS; ++ss) {
    uint4 v = *(const uint4*)(h1 + (long)(m * NS + ss) * 256 + d8 * 8);
    unsigned vals[4] = {v.x, v.y, v.z, v.w};
#pragma unroll
    for (int x = 0; x < 4; ++x) {
      s[x * 2]     += bf2f((unsigned short)(vals[x] & 0xFFFF));
      s[x * 2 + 1] += bf2f((unsigned short)(vals[x] >> 16));
    }
  }
  uint4 o;
  o.x = pk2(s[0] * 0.1f, s[1] * 0.1f);
  o.y = pk2(s[2] * 0.1f, s[3] * 0.1f);
  o.z = pk2(s[4] * 0.1f, s[5] * 0.1f);
  o.w = pk2(s[6] * 0.1f, s[7] * 0.1f);
  *(uint4*)(A3 + (long)mp * (512L * 576) + (long)m * 576 + 256 + d8 * 8) = o;
}

__global__ __launch_bounds__(256) void p3_k(
    const unsigned short* __restrict__ h01, const unsigned short* __restrict__ eg0,
    const unsigned short* __restrict__ wte, const float* __restrict__ bec,
    unsigned short* __restrict__ enew, unsigned short* __restrict__ A3) {
  int j = blockIdx.x;
  if (j < 160) edge_tile(j, h01, eg0, wte, bec, enew, threadIdx.x);
  else h1mean_item((j - 160) * 256 + threadIdx.x, h01, A3);
}

// ===== GEMM3: osum = [A3 cols 0..511 | mean10(enew)] @ WT1[mp][1] ==========
// BM=64 BN=64, LDS-free; e-mean fragment computed in-register (same rounding
// as before: f32 mean -> bf16 pack).
__device__ __forceinline__ bf16x8 emean_frag(const unsigned short* en, int gr,
                                             int koff, int quad) {
  float s[8];
#pragma unroll
  for (int x = 0; x < 8; ++x) s[x] = 0.f;
#pragma unroll
  for (int ss = 0; ss < NS; ++ss) {
    uint4 v = *(const uint4*)(en + ((long)gr * NS + ss) * 64 + koff + quad * 8);
    unsigned vals[4] = {v.x, v.y, v.z, v.w};
#pragma unroll
    for (int x = 0; x < 4; ++x) {
      s[x * 2]     += bf2f((unsigned short)(vals[x] & 0xFFFF));
      s[x * 2 + 1] += bf2f((unsigned short)(vals[x] >> 16));
    }
  }
  union { uint4 u; bf16x8 h; } o;
  o.u.x = pk2(s[0] * 0.1f, s[1] * 0.1f);
  o.u.y = pk2(s[2] * 0.1f, s[3] * 0.1f);
  o.u.z = pk2(s[4] * 0.1f, s[5] * 0.1f);
  o.u.w = pk2(s[6] * 0.1f, s[7] * 0.1f);
  return o.h;
}

__global__ __launch_bounds__(256) void gemm3_k(
    const unsigned short* __restrict__ A3, const unsigned short* __restrict__ enew,
    const unsigned short* __restrict__ wt1, float* __restrict__ osum) {
  int tid = threadIdx.x, tile = blockIdx.x;
  int mp = tile & 1, t2 = tile >> 1;
  int n0 = (t2 & 3) * 64, m0 = (t2 >> 2) * 64;
  const unsigned short* Ap = A3 + (long)mp * (512L * 576) + (long)m0 * 576;
  const unsigned short* en = enew + (long)mp * (5120L * 64);
  const unsigned short* Bp = wt1 + (long)(mp * 2 + 1) * 147456 + (long)n0 * 576;

  int wave = tid >> 6, lane = tid & 63;
  int wm = wave >> 1, wn = wave & 1;
  int quad = lane >> 4, r16 = lane & 15;

  const unsigned short *pa[2], *pb[2];
  int grw[2];
#pragma unroll
  for (int i = 0; i < 2; ++i) {
    int row = wm * 32 + i * 16 + r16;
    pa[i] = Ap + (long)row * 576 + quad * 8;
    grw[i] = m0 + row;
  }
#pragma unroll
  for (int j = 0; j < 2; ++j)
    pb[j] = Bp + (long)(wn * 32 + j * 16 + r16) * 576 + quad * 8;

  f32x4 acc[2][2];
#pragma unroll
  for (int i = 0; i < 2; ++i)
#pragma unroll
    for (int j = 0; j < 2; ++j) acc[i][j] = (f32x4){0.f, 0.f, 0.f, 0.f};

#pragma unroll
  for (int it = 0; it < 16; ++it) {  // k 0..511 from A3
    bf16x8 av[2], bv[2];
#pragma unroll
    for (int i = 0; i < 2; ++i) av[i] = *(const bf16x8*)(pa[i] + it * 32);
#pragma unroll
    for (int j = 0; j < 2; ++j) bv[j] = *(const bf16x8*)(pb[j] + it * 32);
#pragma unroll
    for (int i = 0; i < 2; ++i)
#pragma unroll
      for (int j = 0; j < 2; ++j)
        acc[i][j] = __builtin_amdgcn_mfma_f32_16x16x32_bf16(av[i], bv[j], acc[i][j], 0, 0, 0);
  }
#pragma unroll
  for (int it = 0; it < 2; ++it) {  // k 512..575: on-the-fly e-mean
    bf16x8 av[2], bv[2];
#pragma unroll
    for (int i = 0; i < 2; ++i) av[i] = emean_frag(en, grw[i], it * 32, quad);
#pragma unroll
    for (int j = 0; j < 2; ++j) bv[j] = *(const bf16x8*)(pb[j] + (16 + it) * 32);
#pragma unroll
    for (int i = 0; i < 2; ++i)
#pragma unroll
      for (int j = 0; j < 2; ++j)
        acc[i][j] = __builtin_amdgcn_mfma_f32_16x16x32_bf16(av[i], bv[j], acc[i][j], 0, 0, 0);
  }
#pragma unroll
  for (int i = 0; i < 2; ++i)
#pragma unroll
    for (int j = 0; j < 2; ++j)
#pragma unroll
      for (int r = 0; r < 4; ++r) {
        int rr = m0 + wm * 32 + i * 16 + quad * 4 + r;
        int cc = n0 + wn * 32 + j * 16 + r16;
        osum[(long)mp * 131072 + (long)rr * 256 + cc] = acc[i][j][r];
      }
}

// ---- finalize: out = normalize((o0+o1)/2) @ fc_w + fc_b; 4 rows/block ----
__global__ __launch_bounds__(256) void finalize_k(
    const float* __restrict__ osum, const float* __restrict__ fcw,
    const float* __restrict__ fcb, float* __restrict__ out) {
  int tid = threadIdx.x;
  int wave = tid >> 6, l = tid & 63;
  int b = blockIdx.x * 4 + wave;
  const float* o0 = osum;
  const float* o1 = osum + 131072;
  float v[4];
  float ss = 0.f;
#pragma unroll
  for (int k = 0; k < 4; ++k) {
    int j = l + 64 * k;
    v[k] = 0.5f * (o0[(long)b * 256 + j] + o1[(long)b * 256 + j]);
    ss += v[k] * v[k];
  }
#pragma unroll
  for (int off = 32; off > 0; off >>= 1) ss += __shfl_down(ss, off);
  ss = __shfl(ss, 0);
  float sc = 1.f / fmaxf(sqrtf(ss), 1e-12f);
  float p[8];
#pragma unroll
  for (int c = 0; c < 8; ++c) p[c] = 0.f;
#pragma unroll
  for (int k = 0; k < 4; ++k) {
    int j = l + 64 * k;
    float vh = v[k] * sc;
#pragma unroll
    for (int c = 0; c < 8; ++c) p[c] += vh * fcw[j * 8 + c];
  }
#pragma unroll
  for (int off = 32; off > 0; off >>= 1) {
#pragma unroll
    for (int c = 0; c < 8; ++c) p[c] += __shfl_down(p[c], off);
  }
  if (l == 0) {
#pragma unroll
    for (int c = 0; c < 8; ++c) out[b * 8 + c] = p[c] + fcb[c];
  }
}

extern "C" void kernel_launch(void* const* d_in, const int* in_sizes, int n_in,
                              void* d_out, int out_size, void* d_ws, size_t ws_size,
                              hipStream_t stream) {
  const int* ids = (const int*)d_in[0];
  const float* feats = (const float*)d_in[1];
  const int* n0i[2] = {(const int*)d_in[2], (const int*)d_in[4]};
  const int* n1i[2] = {(const int*)d_in[3], (const int*)d_in[5]};
  const int* e0i[2] = {(const int*)d_in[6], (const int*)d_in[8]};
  const int* e1i[2] = {(const int*)d_in[7], (const int*)d_in[9]};
  const float* emb[2] = {(const float*)d_in[10], (const float*)d_in[11]};
  const float* Wself = (const float*)d_in[12];
  const float* Wneigh = (const float*)d_in[13];
  const float* Wedg = (const float*)d_in[14];
  const float* Wec = (const float*)d_in[15];
  const float* bec = (const float*)d_in[16];
  const float* fcw = (const float*)d_in[17];
  const float* fcb = (const float*)d_in[18];
  float* out = (float*)d_out;

  // ---- workspace ----
  float* osum = (float*)d_ws;                               // [2][512][256] f32
  unsigned short* A1b  = (unsigned short*)(osum + 262144);  // [2][5632][576]
  unsigned short* eg0  = A1b + 6488064;                     // [2][5120][64]
  unsigned short* h01  = eg0 + 655360;                      // [2][5632][256]
  unsigned short* enew = h01 + 2883584;                     // [2][5120][64]
  unsigned short* wt1  = enew + 655360;                     // [4][256][576]
  unsigned short* wte  = wt1 + 589824;                      // [2][64][576]
  unsigned short* A3   = wte + 73728;                       // [2][512][576]

  // ---- gather jobs (dual jobs fuse direct-copy + mean over same rows) ----
  GJobs gj; int blk = 0, nj = 0;
  {
    auto add = [&](const float* table, const int* idx, unsigned short* o,
                   int M, int D4, int ns, int ostride, float inv,
                   unsigned short* o2, int ostride2) {
      gj.j[nj] = {table, idx, o, o2, M, D4, ns, ostride, ostride2, blk, inv};
      blk += (M * D4) / 256; ++nj;
    };
    for (int mp = 0; mp < 2; ++mp) {
      unsigned short* Am = A1b + (size_t)mp * 5632 * 576;
      add(feats, ids, Am, 512, 64, 1, 576, 1.0f, nullptr, 0);
      add(feats, n0i[mp], Am + 256, 512, 64, NS, 576, 0.1f, Am + 512 * 576, 576);
      add(feats, n1i[mp], Am + 512 * 576 + 256, 5120, 64, NS, 576, 0.1f, nullptr, 0);
      add(emb[mp], e0i[mp], Am + 512, 512, 16, NS, 576, 0.1f,
          eg0 + (size_t)mp * 327680, 64);
      add(emb[mp], e1i[mp], Am + 512 * 576 + 512, 5120, 16, NS, 576, 0.1f, nullptr, 0);
    }
  }

  // 1) prep: weight pack + gathers
  gprep_k<<<dim3(PACKB + blk), dim3(256), 0, stream>>>(
      gj, nj, Wself, Wneigh, Wedg, Wec, wt1, wte);

  // 2) layer-0 agg (704 tiles); tees h0 rows into A3
  gemm1_k<<<dim3(704), dim3(256), 0, stream>>>(A1b, wt1, h01, A3);

  // 3) edge GEMM (160 tiles) || h1-means (128 blocks)
  p3_k<<<dim3(288), dim3(256), 0, stream>>>(h01, eg0, wte, bec, enew, A3);

  // 4) layer-1 agg with on-the-fly e-means (64 tiles)
  gemm3_k<<<dim3(64), dim3(256), 0, stream>>>(A3, enew, wt1, osum);

  // 5) metapath mean + L2 normalize + FC
  finalize_k<<<dim3(128), dim3(256), 0, stream>>>(osum, fcw, fcb, out);
}

// Round 7
// 266.254 us; speedup vs baseline: 1.0944x; 1.0944x over previous
//
#include <hip/hip_runtime.h>

#define NS 10
#define PACKB 2592  // (2*2*256*576 + 2*64*576) / 256

typedef __attribute__((ext_vector_type(8))) short bf16x8;
typedef __attribute__((ext_vector_type(4))) float f32x4;

__device__ __forceinline__ float bf2f(unsigned short u) {
  union { unsigned int i; float f; } x;
  x.i = ((unsigned int)u) << 16;
  return x.f;
}
__device__ __forceinline__ unsigned short f2bf(float f) {
  union { float f; unsigned int i; } x; x.f = f;
  unsigned int r = x.i + 0x7FFFu + ((x.i >> 16) & 1u);
  return (unsigned short)(r >> 16);
}
__device__ __forceinline__ unsigned pk2(float a, float b) {
  return (unsigned)f2bf(a) | ((unsigned)f2bf(b) << 16);
}

// ===== gprep: weight pack + gathers; dual jobs write direct rows AND mean ===
struct GJob {
  const float* table; const int* idx;
  unsigned short* out; unsigned short* out2;   // out2: direct rows (dual jobs)
  int M, D4, ns, ostride, ostride2, blk0; float inv;
};
struct GJobs { GJob j[10]; };

__global__ __launch_bounds__(256) void gprep_k(
    GJobs js, int njobs,
    const float* __restrict__ Wself, const float* __restrict__ Wneigh,
    const float* __restrict__ Wedg, const float* __restrict__ Wec,
    unsigned short* __restrict__ wt1, unsigned short* __restrict__ wte) {
  int b = blockIdx.x;
  if (b < PACKB) {
    int t = b * 256 + threadIdx.x;
    const int total1 = 2 * 2 * 256 * 576;
    if (t < total1) {
      int g = t / 147456, r = t - g * 147456;
      int n = r / 576, k = r - n * 576;
      float v;
      if (k < 256) v = Wself[(long)g * 65536 + k * 256 + n];
      else if (k < 512) v = Wneigh[(long)g * 65536 + (k - 256) * 256 + n];
      else v = Wedg[(long)g * 16384 + (k - 512) * 256 + n];
      wt1[t] = f2bf(v);
    } else {
      int t2 = t - total1;  // < 2*64*576
      int mp = t2 / 36864, r = t2 - mp * 36864;
      int n = r / 576, k = r - n * 576;
      wte[t2] = f2bf(Wec[(long)(mp * 2) * 36864 + k * 64 + n]);
    }
    return;
  }
  b -= PACKB;
  int ji = 0;
  for (int k = 1; k < njobs; ++k) if (b >= js.j[k].blk0) ji = k;
  GJob jb = js.j[ji];
  int t = (b - jb.blk0) * 256 + threadIdx.x;
  int m = t / jb.D4, d4 = t - m * jb.D4;
  long D = (long)jb.D4 * 4;
  float ax = 0.f, ay = 0.f, az = 0.f, aw = 0.f;
  if (jb.ns == NS) {
    // For D4==64 jobs a wave spans exactly one row -> m is wave-uniform.
    // Hoist the 10 index loads to the scalar path (64x dedup, saddr gathers).
    const int* ip;
    if (jb.D4 == 64) {
      int mu = __builtin_amdgcn_readfirstlane(m);
      ip = jb.idx + (long)mu * NS;
    } else {
      ip = jb.idx + (long)m * NS;
    }
    int ridx[NS];
#pragma unroll
    for (int s = 0; s < NS; ++s) ridx[s] = ip[s];
    float4 vv[NS];
#pragma unroll
    for (int s = 0; s < NS; ++s)
      vv[s] = *(const float4*)(jb.table + (long)ridx[s] * D + d4 * 4);
#pragma unroll
    for (int s = 0; s < NS; ++s) {
      ax += vv[s].x; ay += vv[s].y; az += vv[s].z; aw += vv[s].w;
    }
    if (jb.out2) {  // dual: also emit the 10 direct rows (scale 1.0)
#pragma unroll
      for (int s = 0; s < NS; ++s) {
        uint2 o2; o2.x = pk2(vv[s].x, vv[s].y); o2.y = pk2(vv[s].z, vv[s].w);
        *(uint2*)(jb.out2 + (long)(m * NS + s) * jb.ostride2 + d4 * 4) = o2;
      }
    }
  } else {
    long r = (long)jb.idx[m];
    float4 v = *(const float4*)(jb.table + r * D + d4 * 4);
    ax = v.x; ay = v.y; az = v.z; aw = v.w;
  }
  uint2 o; o.x = pk2(ax * jb.inv, ay * jb.inv); o.y = pk2(az * jb.inv, aw * jb.inv);
  *(uint2*)(jb.out + (long)m * jb.ostride + d4 * 4) = o;
}

// ===== GEMM1: h01 = relu(A1b @ WT1[mp][0]); BM=64 BN=64, 2-deep prefetch ====
// Tees rows<512 into A3[mp][512][576] cols 0..255. 704 tiles.
__global__ __launch_bounds__(256) void gemm1_k(
    const unsigned short* __restrict__ A, const unsigned short* __restrict__ wt1,
    unsigned short* __restrict__ C, unsigned short* __restrict__ A3) {
  __shared__ unsigned short As[2][2560];
  __shared__ unsigned short Bs[2][2560];
  int tid = threadIdx.x, tile = blockIdx.x;
  int mp = tile & 1, t2 = tile >> 1;
  int n0 = (t2 & 3) * 64, m0 = (t2 >> 2) * 64;
  const unsigned short* Ap = A + (long)mp * (5632L * 576) + (long)m0 * 576;
  const unsigned short* Bp = wt1 + (long)mp * 2 * 147456 + (long)n0 * 576;
  int row = tid >> 2, q = tid & 3;
  const unsigned short* apt = Ap + (long)row * 576 + q * 8;
  const unsigned short* bpt = Bp + (long)row * 576 + q * 8;

  {  // prologue: stage it=0, issue it=1
    uint4 a0 = *(const uint4*)apt;
    uint4 b0 = *(const uint4*)bpt;
    *(uint4*)&As[0][row * 40 + q * 8] = a0;
    *(uint4*)&Bs[0][row * 40 + q * 8] = b0;
  }
  uint4 an = *(const uint4*)(apt + 32);
  uint4 bn = *(const uint4*)(bpt + 32);
  __syncthreads();

  f32x4 acc[2][2];
#pragma unroll
  for (int i = 0; i < 2; ++i)
#pragma unroll
    for (int j = 0; j < 2; ++j) acc[i][j] = (f32x4){0.f, 0.f, 0.f, 0.f};

  int wave = tid >> 6, lane = tid & 63;
  int wm = wave >> 1, wn = wave & 1;
  int quad = lane >> 4, r16 = lane & 15;

  for (int it = 0; it < 18; ++it) {
    uint4 af_, bf_;
    if (it + 2 < 18) {  // deepest prefetch: issue it+2 now
      af_ = *(const uint4*)(apt + (it + 2) * 32);
      bf_ = *(const uint4*)(bpt + (it + 2) * 32);
    }
    int c = it & 1;
    bf16x8 av[2], bv[2];
#pragma unroll
    for (int i = 0; i < 2; ++i)
      av[i] = *(const bf16x8*)&As[c][(wm * 32 + i * 16 + r16) * 40 + quad * 8];
#pragma unroll
    for (int j = 0; j < 2; ++j)
      bv[j] = *(const bf16x8*)&Bs[c][(wn * 32 + j * 16 + r16) * 40 + quad * 8];
#pragma unroll
    for (int i = 0; i < 2; ++i)
#pragma unroll
      for (int j = 0; j < 2; ++j)
        acc[i][j] = __builtin_amdgcn_mfma_f32_16x16x32_bf16(av[i], bv[j], acc[i][j], 0, 0, 0);
    if (it + 1 < 18) {  // land it+1 (issued last iteration)
      *(uint4*)&As[c ^ 1][row * 40 + q * 8] = an;
      *(uint4*)&Bs[c ^ 1][row * 40 + q * 8] = bn;
      __syncthreads();
    }
    an = af_; bn = bf_;
  }
#pragma unroll
  for (int i = 0; i < 2; ++i)
#pragma unroll
    for (int j = 0; j < 2; ++j)
#pragma unroll
      for (int r = 0; r < 4; ++r) {
        int rr = m0 + wm * 32 + i * 16 + quad * 4 + r;
        int cc = n0 + wn * 32 + j * 16 + r16;
        unsigned short u = f2bf(fmaxf(acc[i][j][r], 0.f));
        C[(long)mp * (5632L * 256) + (long)rr * 256 + cc] = u;
        if (rr < 512)
          A3[(long)mp * (512L * 576) + (long)rr * 576 + cc] = u;
      }
}

// ===== P3: edge GEMM (160 tiles) || h1-means (128 block-jobs) ==============
__device__ __forceinline__ const unsigned short* edgeA(
    const unsigned short* h0, const unsigned short* h1, const unsigned short* eg,
    int ar0, int gr, int q, int it) {
  if (it < 8)  return h0 + (long)ar0 * 256 + it * 32 + q * 8;
  if (it < 16) return h1 + (long)gr * 256 + (it - 8) * 32 + q * 8;
  return eg + (long)gr * 64 + (it - 16) * 32 + q * 8;
}

__device__ void edge_tile(int tile, const unsigned short* h01, const unsigned short* eg0,
                          const unsigned short* wte, const float* bec,
                          unsigned short* enew, unsigned short* sm, int tid) {
  unsigned short* As = sm;         // [2][2560]
  unsigned short* Bs = sm + 5120;  // [2][2560]
  int mp = tile & 1;
  int m0 = (tile >> 1) * 64;
  const unsigned short* h0 = h01 + (long)mp * (5632L * 256);
  const unsigned short* h1 = h0 + 512 * 256;
  const unsigned short* eg = eg0 + (long)mp * (5120L * 64);
  const unsigned short* Bp = wte + (long)mp * 36864;

  int row = tid >> 2, q = tid & 3;
  int gr = m0 + row;
  int ar0 = gr / 10;
  const unsigned short* bpt = Bp + (long)row * 576 + q * 8;

  {
    uint4 a = *(const uint4*)edgeA(h0, h1, eg, ar0, gr, q, 0);
    uint4 bv = *(const uint4*)bpt;
    *(uint4*)&As[row * 40 + q * 8] = a;
    *(uint4*)&Bs[row * 40 + q * 8] = bv;
  }
  uint4 an = *(const uint4*)edgeA(h0, h1, eg, ar0, gr, q, 1);
  uint4 bn = *(const uint4*)(bpt + 32);
  __syncthreads();

  f32x4 acc[2][2];
#pragma unroll
  for (int i = 0; i < 2; ++i)
#pragma unroll
    for (int j = 0; j < 2; ++j) acc[i][j] = (f32x4){0.f, 0.f, 0.f, 0.f};

  int wave = tid >> 6, lane = tid & 63;
  int wm = wave >> 1, wn = wave & 1;
  int quad = lane >> 4, r16 = lane & 15;

  for (int it = 0; it < 18; ++it) {
    uint4 af_, bf_;
    if (it + 2 < 18) {
      af_ = *(const uint4*)edgeA(h0, h1, eg, ar0, gr, q, it + 2);
      bf_ = *(const uint4*)(bpt + (it + 2) * 32);
    }
    int c = it & 1;
    bf16x8 av[2], bv[2];
#pragma unroll
    for (int i = 0; i < 2; ++i)
      av[i] = *(const bf16x8*)&As[c * 2560 + (wm * 32 + i * 16 + r16) * 40 + quad * 8];
#pragma unroll
    for (int j = 0; j < 2; ++j)
      bv[j] = *(const bf16x8*)&Bs[c * 2560 + (wn * 32 + j * 16 + r16) * 40 + quad * 8];
#pragma unroll
    for (int i = 0; i < 2; ++i)
#pragma unroll
      for (int j = 0; j < 2; ++j)
        acc[i][j] = __builtin_amdgcn_mfma_f32_16x16x32_bf16(av[i], bv[j], acc[i][j], 0, 0, 0);
    if (it + 1 < 18) {
      *(uint4*)&As[(c ^ 1) * 2560 + row * 40 + q * 8] = an;
      *(uint4*)&Bs[(c ^ 1) * 2560 + row * 40 + q * 8] = bn;
      __syncthreads();
    }
    an = af_; bn = bf_;
  }
#pragma unroll
  for (int i = 0; i < 2; ++i)
#pragma unroll
    for (int j = 0; j < 2; ++j)
#pragma unroll
      for (int r = 0; r < 4; ++r) {
        int rr = m0 + wm * 32 + i * 16 + quad * 4 + r;
        int cc = wn * 32 + j * 16 + r16;
        float v = tanhf(acc[i][j][r] + bec[mp * 128 + cc]);
        enew[(long)mp * (5120L * 64) + (long)rr * 64 + cc] = f2bf(v);
      }
}

__device__ __forceinline__ void h1mean_item(int t, const unsigned short* h01,
                                            unsigned short* A3) {
  // t in [0, 32768): mp = t>>14, m = (t&16383)>>5, d8 = t&31
  int mp = t >> 14, t14 = t & 16383;
  int m = t14 >> 5, d8 = t14 & 31;
  const unsigned short* h1 = h01 + (long)mp * (5632L * 256) + 512 * 256;
  float s[8];
#pragma unroll
  for (int x = 0; x < 8; ++x) s[x] = 0.f;
#pragma unroll
  for (int ss = 0; ss < NS; ++ss) {
    uint4 v = *(const uint4*)(h1 + (long)(m * NS + ss) * 256 + d8 * 8);
    unsigned vals[4] = {v.x, v.y, v.z, v.w};
#pragma unroll
    for (int x = 0; x < 4; ++x) {
      s[x * 2]     += bf2f((unsigned short)(vals[x] & 0xFFFF));
      s[x * 2 + 1] += bf2f((unsigned short)(vals[x] >> 16));
    }
  }
  uint4 o;
  o.x = pk2(s[0] * 0.1f, s[1] * 0.1f);
  o.y = pk2(s[2] * 0.1f, s[3] * 0.1f);
  o.z = pk2(s[4] * 0.1f, s[5] * 0.1f);
  o.w = pk2(s[6] * 0.1f, s[7] * 0.1f);
  *(uint4*)(A3 + (long)mp * (512L * 576) + (long)m * 576 + 256 + d8 * 8) = o;
}

__global__ __launch_bounds__(256) void p3_k(
    const unsigned short* __restrict__ h01, const unsigned short* __restrict__ eg0,
    const unsigned short* __restrict__ wte, const float* __restrict__ bec,
    unsigned short* __restrict__ enew, unsigned short* __restrict__ A3) {
  __shared__ unsigned short sm[10240];
  int j = blockIdx.x;
  if (j < 160) edge_tile(j, h01, eg0, wte, bec, enew, sm, threadIdx.x);
  else h1mean_item((j - 160) * 256 + threadIdx.x, h01, A3);
}

// ===== GEMM3: osum = [A3 cols 0..511 | mean10(enew)] @ WT1[mp][1] ==========
// BM=64 BN=64, 2-deep; e-mean computed on the fly in the A-stage (it>=16).
__device__ __forceinline__ uint4 g3A(const unsigned short* apt,
                                     const unsigned short* en, int gr, int q, int it) {
  if (it < 16) return *(const uint4*)(apt + it * 32);
  float s[8];
#pragma unroll
  for (int x = 0; x < 8; ++x) s[x] = 0.f;
#pragma unroll
  for (int ss = 0; ss < NS; ++ss) {
    uint4 v = *(const uint4*)(en + (long)(gr * NS + ss) * 64 + (it - 16) * 32 + q * 8);
    unsigned vals[4] = {v.x, v.y, v.z, v.w};
#pragma unroll
    for (int x = 0; x < 4; ++x) {
      s[x * 2]     += bf2f((unsigned short)(vals[x] & 0xFFFF));
      s[x * 2 + 1] += bf2f((unsigned short)(vals[x] >> 16));
    }
  }
  uint4 o;
  o.x = pk2(s[0] * 0.1f, s[1] * 0.1f);
  o.y = pk2(s[2] * 0.1f, s[3] * 0.1f);
  o.z = pk2(s[4] * 0.1f, s[5] * 0.1f);
  o.w = pk2(s[6] * 0.1f, s[7] * 0.1f);
  return o;
}

__global__ __launch_bounds__(256) void gemm3_k(
    const unsigned short* __restrict__ A3, const unsigned short* __restrict__ enew,
    const unsigned short* __restrict__ wt1, float* __restrict__ osum) {
  __shared__ unsigned short As[2][2560];
  __shared__ unsigned short Bs[2][2560];
  int tid = threadIdx.x, tile = blockIdx.x;
  int mp = tile & 1, t2 = tile >> 1;
  int n0 = (t2 & 3) * 64, m0 = (t2 >> 2) * 64;
  const unsigned short* Ap = A3 + (long)mp * (512L * 576) + (long)m0 * 576;
  const unsigned short* en = enew + (long)mp * (5120L * 64);
  const unsigned short* Bp = wt1 + (long)(mp * 2 + 1) * 147456 + (long)n0 * 576;

  int row = tid >> 2, q = tid & 3;
  int gr = m0 + row;
  const unsigned short* apt = Ap + (long)row * 576 + q * 8;
  const unsigned short* bpt = Bp + (long)row * 576 + q * 8;

  {
    uint4 a = g3A(apt, en, gr, q, 0);
    uint4 bv = *(const uint4*)bpt;
    *(uint4*)&As[0][row * 40 + q * 8] = a;
    *(uint4*)&Bs[0][row * 40 + q * 8] = bv;
  }
  uint4 an = g3A(apt, en, gr, q, 1);
  uint4 bn = *(const uint4*)(bpt + 32);
  __syncthreads();

  f32x4 acc[2][2];
#pragma unroll
  for (int i = 0; i < 2; ++i)
#pragma unroll
    for (int j = 0; j < 2; ++j) acc[i][j] = (f32x4){0.f, 0.f, 0.f, 0.f};

  int wave = tid >> 6, lane = tid & 63;
  int wm = wave >> 1, wn = wave & 1;
  int quad = lane >> 4, r16 = lane & 15;

  for (int it = 0; it < 18; ++it) {
    uint4 af_, bf_;
    if (it + 2 < 18) {
      af_ = g3A(apt, en, gr, q, it + 2);
      bf_ = *(const uint4*)(bpt + (it + 2) * 32);
    }
    int c = it & 1;
    bf16x8 av[2], bv[2];
#pragma unroll
    for (int i = 0; i < 2; ++i)
      av[i] = *(const bf16x8*)&As[c][(wm * 32 + i * 16 + r16) * 40 + quad * 8];
#pragma unroll
    for (int j = 0; j < 2; ++j)
      bv[j] = *(const bf16x8*)&Bs[c][(wn * 32 + j * 16 + r16) * 40 + quad * 8];
#pragma unroll
    for (int i = 0; i < 2; ++i)
#pragma unroll
      for (int j = 0; j < 2; ++j)
        acc[i][j] = __builtin_amdgcn_mfma_f32_16x16x32_bf16(av[i], bv[j], acc[i][j], 0, 0, 0);
    if (it + 1 < 18) {
      *(uint4*)&As[c ^ 1][row * 40 + q * 8] = an;
      *(uint4*)&Bs[c ^ 1][row * 40 + q * 8] = bn;
      __syncthreads();
    }
    an = af_; bn = bf_;
  }
#pragma unroll
  for (int i = 0; i < 2; ++i)
#pragma unroll
    for (int j = 0; j < 2; ++j)
#pragma unroll
      for (int r = 0; r < 4; ++r) {
        int rr = m0 + wm * 32 + i * 16 + quad * 4 + r;
        int cc = n0 + wn * 32 + j * 16 + r16;
        osum[(long)mp * 131072 + (long)rr * 256 + cc] = acc[i][j][r];
      }
}

// ---- finalize: out = normalize((o0+o1)/2) @ fc_w + fc_b; 4 rows/block ----
__global__ __launch_bounds__(256) void finalize_k(
    const float* __restrict__ osum, const float* __restrict__ fcw,
    const float* __restrict__ fcb, float* __restrict__ out) {
  int tid = threadIdx.x;
  int wave = tid >> 6, l = tid & 63;
  int b = blockIdx.x * 4 + wave;
  const float* o0 = osum;
  const float* o1 = osum + 131072;
  float v[4];
  float ss = 0.f;
#pragma unroll
  for (int k = 0; k < 4; ++k) {
    int j = l + 64 * k;
    v[k] = 0.5f * (o0[(long)b * 256 + j] + o1[(long)b * 256 + j]);
    ss += v[k] * v[k];
  }
#pragma unroll
  for (int off = 32; off > 0; off >>= 1) ss += __shfl_down(ss, off);
  ss = __shfl(ss, 0);
  float sc = 1.f / fmaxf(sqrtf(ss), 1e-12f);
  float p[8];
#pragma unroll
  for (int c = 0; c < 8; ++c) p[c] = 0.f;
#pragma unroll
  for (int k = 0; k < 4; ++k) {
    int j = l + 64 * k;
    float vh = v[k] * sc;
#pragma unroll
    for (int c = 0; c < 8; ++c) p[c] += vh * fcw[j * 8 + c];
  }
#pragma unroll
  for (int off = 32; off > 0; off >>= 1) {
#pragma unroll
    for (int c = 0; c < 8; ++c) p[c] += __shfl_down(p[c], off);
  }
  if (l == 0) {
#pragma unroll
    for (int c = 0; c < 8; ++c) out[b * 8 + c] = p[c] + fcb[c];
  }
}

extern "C" void kernel_launch(void* const* d_in, const int* in_sizes, int n_in,
                              void* d_out, int out_size, void* d_ws, size_t ws_size,
                              hipStream_t stream) {
  const int* ids = (const int*)d_in[0];
  const float* feats = (const float*)d_in[1];
  const int* n0i[2] = {(const int*)d_in[2], (const int*)d_in[4]};
  const int* n1i[2] = {(const int*)d_in[3], (const int*)d_in[5]};
  const int* e0i[2] = {(const int*)d_in[6], (const int*)d_in[8]};
  const int* e1i[2] = {(const int*)d_in[7], (const int*)d_in[9]};
  const float* emb[2] = {(const float*)d_in[10], (const float*)d_in[11]};
  const float* Wself = (const float*)d_in[12];
  const float* Wneigh = (const float*)d_in[13];
  const float* Wedg = (const float*)d_in[14];
  const float* Wec = (const float*)d_in[15];
  const float* bec = (const float*)d_in[16];
  const float* fcw = (const float*)d_in[17];
  const float* fcb = (const float*)d_in[18];
  float* out = (float*)d_out;

  // ---- workspace ----
  float* osum = (float*)d_ws;                               // [2][512][256] f32
  unsigned short* A1b  = (unsigned short*)(osum + 262144);  // [2][5632][576]
  unsigned short* eg0  = A1b + 6488064;                     // [2][5120][64]
  unsigned short* h01  = eg0 + 655360;                      // [2][5632][256]
  unsigned short* enew = h01 + 2883584;                     // [2][5120][64]
  unsigned short* wt1  = enew + 655360;                     // [4][256][576]
  unsigned short* wte  = wt1 + 589824;                      // [2][64][576]
  unsigned short* A3   = wte + 73728;                       // [2][512][576]

  // ---- gather jobs (dual jobs fuse direct-copy + mean over same rows) ----
  GJobs gj; int blk = 0, nj = 0;
  {
    auto add = [&](const float* table, const int* idx, unsigned short* o,
                   int M, int D4, int ns, int ostride, float inv,
                   unsigned short* o2, int ostride2) {
      gj.j[nj] = {table, idx, o, o2, M, D4, ns, ostride, ostride2, blk, inv};
      blk += (M * D4) / 256; ++nj;
    };
    for (int mp = 0; mp < 2; ++mp) {
      unsigned short* Am = A1b + (size_t)mp * 5632 * 576;
      add(feats, ids, Am, 512, 64, 1, 576, 1.0f, nullptr, 0);
      add(feats, n0i[mp], Am + 256, 512, 64, NS, 576, 0.1f, Am + 512 * 576, 576);
      add(feats, n1i[mp], Am + 512 * 576 + 256, 5120, 64, NS, 576, 0.1f, nullptr, 0);
      add(emb[mp], e0i[mp], Am + 512, 512, 16, NS, 576, 0.1f,
          eg0 + (size_t)mp * 327680, 64);
      add(emb[mp], e1i[mp], Am + 512 * 576 + 512, 5120, 16, NS, 576, 0.1f, nullptr, 0);
    }
  }

  // 1) prep: weight pack + gathers
  gprep_k<<<dim3(PACKB + blk), dim3(256), 0, stream>>>(
      gj, nj, Wself, Wneigh, Wedg, Wec, wt1, wte);

  // 2) layer-0 agg (704 tiles); tees h0 rows into A3
  gemm1_k<<<dim3(704), dim3(256), 0, stream>>>(A1b, wt1, h01, A3);

  // 3) edge GEMM (160 tiles) || h1-means (128 blocks)
  p3_k<<<dim3(288), dim3(256), 0, stream>>>(h01, eg0, wte, bec, enew, A3);

  // 4) layer-1 agg with on-the-fly e-means (64 tiles)
  gemm3_k<<<dim3(64), dim3(256), 0, stream>>>(A3, enew, wt1, osum);

  // 5) metapath mean + L2 normalize + FC
  finalize_k<<<dim3(128), dim3(256), 0, stream>>>(osum, fcw, fcb, out);
}

// Round 8
// 262.501 us; speedup vs baseline: 1.1100x; 1.0143x over previous
//
#include <hip/hip_runtime.h>

#define NS 10
#define PACKT 162  // transpose tiles: 144 (wt1) + 18 (wte)

typedef __attribute__((ext_vector_type(8))) short bf16x8;
typedef __attribute__((ext_vector_type(4))) float f32x4;

__device__ __forceinline__ float bf2f(unsigned short u) {
  union { unsigned int i; float f; } x;
  x.i = ((unsigned int)u) << 16;
  return x.f;
}
__device__ __forceinline__ unsigned short f2bf(float f) {
  union { float f; unsigned int i; } x; x.f = f;
  unsigned int r = x.i + 0x7FFFu + ((x.i >> 16) & 1u);
  return (unsigned short)(r >> 16);
}
__device__ __forceinline__ unsigned pk2(float a, float b) {
  return (unsigned)f2bf(a) | ((unsigned)f2bf(b) << 16);
}

// ===== gprep: weight pack (LDS transpose, coalesced) + gathers ==============
struct GJob {
  const float* table; const int* idx;
  unsigned short* out; unsigned short* out2;   // out2: direct rows (dual jobs)
  int M, D4, ns, ostride, ostride2, blk0; float inv;
};
struct GJobs { GJob j[10]; };

__global__ __launch_bounds__(256) void gprep_k(
    GJobs js, int njobs,
    const float* __restrict__ Wself, const float* __restrict__ Wneigh,
    const float* __restrict__ Wedg, const float* __restrict__ Wec,
    unsigned short* __restrict__ wt1, unsigned short* __restrict__ wte) {
  int b = blockIdx.x;
  if (b < PACKT) {
    // 64x64 transpose tile via LDS: coalesced read [k][n], coalesced write [n][k]
    __shared__ float T[64][65];
    int tid = threadIdx.x;
    const float* src; int srcS, kbase, nbase; unsigned short* dst;
    if (b < 144) {            // wt1: g = b/36, kt = (b%36)/4, nt = (b%36)%4
      int g = b / 36, r = b - g * 36;
      int kt = r >> 2, nt = r & 3;
      kbase = kt * 64; nbase = nt * 64;
      if (kbase < 256)      { src = Wself + (long)g * 65536 + (long)kbase * 256 + nbase; }
      else if (kbase < 512) { src = Wneigh + (long)g * 65536 + (long)(kbase - 256) * 256 + nbase; }
      else                  { src = Wedg + (long)g * 16384 + (long)(kbase - 512) * 256 + nbase; }
      srcS = 256;
      dst = wt1 + (long)g * 147456;
    } else {                  // wte: mp = (b-144)/9, kt = (b-144)%9
      int t2 = b - 144;
      int mp = t2 / 9, kt = t2 - mp * 9;
      kbase = kt * 64; nbase = 0;
      src = Wec + (long)(mp * 2) * 36864 + (long)kbase * 64;
      srcS = 64;
      dst = wte + (long)mp * 36864;
    }
    int nl = tid & 63, kq = tid >> 6;
#pragma unroll
    for (int p = 0; p < 16; ++p) {
      int kl = kq * 16 + p;
      T[kl][nl] = src[(long)kl * srcS + nl];
    }
    __syncthreads();
    int kl2 = tid & 63, nq = tid >> 6;
#pragma unroll
    for (int p = 0; p < 16; ++p) {
      int nl2 = nq * 16 + p;
      dst[(long)(nbase + nl2) * 576 + kbase + kl2] = f2bf(T[kl2][nl2]);
    }
    return;
  }
  b -= PACKT;
  int ji = 0;
  for (int k = 1; k < njobs; ++k) if (b >= js.j[k].blk0) ji = k;
  GJob jb = js.j[ji];
  int t = (b - jb.blk0) * 256 + threadIdx.x;
  int m = t / jb.D4, d4 = t - m * jb.D4;
  long D = (long)jb.D4 * 4;
  float ax = 0.f, ay = 0.f, az = 0.f, aw = 0.f;
  if (jb.ns == NS) {
    // For D4==64 jobs a wave spans exactly one row -> m is wave-uniform.
    const int* ip;
    if (jb.D4 == 64) {
      int mu = __builtin_amdgcn_readfirstlane(m);
      ip = jb.idx + (long)mu * NS;
    } else {
      ip = jb.idx + (long)m * NS;
    }
    int ridx[NS];
#pragma unroll
    for (int s = 0; s < NS; ++s) ridx[s] = ip[s];
    float4 vv[NS];
#pragma unroll
    for (int s = 0; s < NS; ++s)
      vv[s] = *(const float4*)(jb.table + (long)ridx[s] * D + d4 * 4);
#pragma unroll
    for (int s = 0; s < NS; ++s) {
      ax += vv[s].x; ay += vv[s].y; az += vv[s].z; aw += vv[s].w;
    }
    if (jb.out2) {  // dual: also emit the 10 direct rows (scale 1.0)
#pragma unroll
      for (int s = 0; s < NS; ++s) {
        uint2 o2; o2.x = pk2(vv[s].x, vv[s].y); o2.y = pk2(vv[s].z, vv[s].w);
        *(uint2*)(jb.out2 + (long)(m * NS + s) * jb.ostride2 + d4 * 4) = o2;
      }
    }
  } else {
    long r = (long)jb.idx[m];
    float4 v = *(const float4*)(jb.table + r * D + d4 * 4);
    ax = v.x; ay = v.y; az = v.z; aw = v.w;
  }
  uint2 o; o.x = pk2(ax * jb.inv, ay * jb.inv); o.y = pk2(az * jb.inv, aw * jb.inv);
  *(uint2*)(jb.out + (long)m * jb.ostride + d4 * 4) = o;
}

// ===== GEMM1: h01 = relu(A1b @ WT1[mp][0]); BM=64 BN=64, 2-deep prefetch ====
// Tees rows<512 into A3[mp][512][576] cols 0..255. 704 tiles.
__global__ __launch_bounds__(256) void gemm1_k(
    const unsigned short* __restrict__ A, const unsigned short* __restrict__ wt1,
    unsigned short* __restrict__ C, unsigned short* __restrict__ A3) {
  __shared__ unsigned short As[2][2560];
  __shared__ unsigned short Bs[2][2560];
  int tid = threadIdx.x, tile = blockIdx.x;
  int mp = tile & 1, t2 = tile >> 1;
  int n0 = (t2 & 3) * 64, m0 = (t2 >> 2) * 64;
  const unsigned short* Ap = A + (long)mp * (5632L * 576) + (long)m0 * 576;
  const unsigned short* Bp = wt1 + (long)mp * 2 * 147456 + (long)n0 * 576;
  int row = tid >> 2, q = tid & 3;
  const unsigned short* apt = Ap + (long)row * 576 + q * 8;
  const unsigned short* bpt = Bp + (long)row * 576 + q * 8;

  {  // prologue: stage it=0, issue it=1
    uint4 a0 = *(const uint4*)apt;
    uint4 b0 = *(const uint4*)bpt;
    *(uint4*)&As[0][row * 40 + q * 8] = a0;
    *(uint4*)&Bs[0][row * 40 + q * 8] = b0;
  }
  uint4 an = *(const uint4*)(apt + 32);
  uint4 bn = *(const uint4*)(bpt + 32);
  __syncthreads();

  f32x4 acc[2][2];
#pragma unroll
  for (int i = 0; i < 2; ++i)
#pragma unroll
    for (int j = 0; j < 2; ++j) acc[i][j] = (f32x4){0.f, 0.f, 0.f, 0.f};

  int wave = tid >> 6, lane = tid & 63;
  int wm = wave >> 1, wn = wave & 1;
  int quad = lane >> 4, r16 = lane & 15;

  for (int it = 0; it < 18; ++it) {
    uint4 af_, bf_;
    if (it + 2 < 18) {  // deepest prefetch: issue it+2 now
      af_ = *(const uint4*)(apt + (it + 2) * 32);
      bf_ = *(const uint4*)(bpt + (it + 2) * 32);
    }
    int c = it & 1;
    bf16x8 av[2], bv[2];
#pragma unroll
    for (int i = 0; i < 2; ++i)
      av[i] = *(const bf16x8*)&As[c][(wm * 32 + i * 16 + r16) * 40 + quad * 8];
#pragma unroll
    for (int j = 0; j < 2; ++j)
      bv[j] = *(const bf16x8*)&Bs[c][(wn * 32 + j * 16 + r16) * 40 + quad * 8];
#pragma unroll
    for (int i = 0; i < 2; ++i)
#pragma unroll
      for (int j = 0; j < 2; ++j)
        acc[i][j] = __builtin_amdgcn_mfma_f32_16x16x32_bf16(av[i], bv[j], acc[i][j], 0, 0, 0);
    if (it + 1 < 18) {  // land it+1 (issued last iteration)
      *(uint4*)&As[c ^ 1][row * 40 + q * 8] = an;
      *(uint4*)&Bs[c ^ 1][row * 40 + q * 8] = bn;
      __syncthreads();
    }
    an = af_; bn = bf_;
  }
#pragma unroll
  for (int i = 0; i < 2; ++i)
#pragma unroll
    for (int j = 0; j < 2; ++j)
#pragma unroll
      for (int r = 0; r < 4; ++r) {
        int rr = m0 + wm * 32 + i * 16 + quad * 4 + r;
        int cc = n0 + wn * 32 + j * 16 + r16;
        unsigned short u = f2bf(fmaxf(acc[i][j][r], 0.f));
        C[(long)mp * (5632L * 256) + (long)rr * 256 + cc] = u;
        if (rr < 512)
          A3[(long)mp * (512L * 576) + (long)rr * 576 + cc] = u;
      }
}

// ===== P3: edge GEMM (160 tiles) || h1-means (128 block-jobs) ==============
__device__ __forceinline__ const unsigned short* edgeA(
    const unsigned short* h0, const unsigned short* h1, const unsigned short* eg,
    int ar0, int gr, int q, int it) {
  if (it < 8)  return h0 + (long)ar0 * 256 + it * 32 + q * 8;
  if (it < 16) return h1 + (long)gr * 256 + (it - 8) * 32 + q * 8;
  return eg + (long)gr * 64 + (it - 16) * 32 + q * 8;
}

__device__ void edge_tile(int tile, const unsigned short* h01, const unsigned short* eg0,
                          const unsigned short* wte, const float* bec,
                          unsigned short* enew, unsigned short* sm, int tid) {
  unsigned short* As = sm;         // [2][2560]
  unsigned short* Bs = sm + 5120;  // [2][2560]
  int mp = tile & 1;
  int m0 = (tile >> 1) * 64;
  const unsigned short* h0 = h01 + (long)mp * (5632L * 256);
  const unsigned short* h1 = h0 + 512 * 256;
  const unsigned short* eg = eg0 + (long)mp * (5120L * 64);
  const unsigned short* Bp = wte + (long)mp * 36864;

  int row = tid >> 2, q = tid & 3;
  int gr = m0 + row;
  int ar0 = gr / 10;
  const unsigned short* bpt = Bp + (long)row * 576 + q * 8;

  {
    uint4 a = *(const uint4*)edgeA(h0, h1, eg, ar0, gr, q, 0);
    uint4 bv = *(const uint4*)bpt;
    *(uint4*)&As[row * 40 + q * 8] = a;
    *(uint4*)&Bs[row * 40 + q * 8] = bv;
  }
  uint4 an = *(const uint4*)edgeA(h0, h1, eg, ar0, gr, q, 1);
  uint4 bn = *(const uint4*)(bpt + 32);
  __syncthreads();

  f32x4 acc[2][2];
#pragma unroll
  for (int i = 0; i < 2; ++i)
#pragma unroll
    for (int j = 0; j < 2; ++j) acc[i][j] = (f32x4){0.f, 0.f, 0.f, 0.f};

  int wave = tid >> 6, lane = tid & 63;
  int wm = wave >> 1, wn = wave & 1;
  int quad = lane >> 4, r16 = lane & 15;

  for (int it = 0; it < 18; ++it) {
    uint4 af_, bf_;
    if (it + 2 < 18) {
      af_ = *(const uint4*)edgeA(h0, h1, eg, ar0, gr, q, it + 2);
      bf_ = *(const uint4*)(bpt + (it + 2) * 32);
    }
    int c = it & 1;
    bf16x8 av[2], bv[2];
#pragma unroll
    for (int i = 0; i < 2; ++i)
      av[i] = *(const bf16x8*)&As[c * 2560 + (wm * 32 + i * 16 + r16) * 40 + quad * 8];
#pragma unroll
    for (int j = 0; j < 2; ++j)
      bv[j] = *(const bf16x8*)&Bs[c * 2560 + (wn * 32 + j * 16 + r16) * 40 + quad * 8];
#pragma unroll
    for (int i = 0; i < 2; ++i)
#pragma unroll
      for (int j = 0; j < 2; ++j)
        acc[i][j] = __builtin_amdgcn_mfma_f32_16x16x32_bf16(av[i], bv[j], acc[i][j], 0, 0, 0);
    if (it + 1 < 18) {
      *(uint4*)&As[(c ^ 1) * 2560 + row * 40 + q * 8] = an;
      *(uint4*)&Bs[(c ^ 1) * 2560 + row * 40 + q * 8] = bn;
      __syncthreads();
    }
    an = af_; bn = bf_;
  }
#pragma unroll
  for (int i = 0; i < 2; ++i)
#pragma unroll
    for (int j = 0; j < 2; ++j)
#pragma unroll
      for (int r = 0; r < 4; ++r) {
        int rr = m0 + wm * 32 + i * 16 + quad * 4 + r;
        int cc = wn * 32 + j * 16 + r16;
        float v = tanhf(acc[i][j][r] + bec[mp * 128 + cc]);
        enew[(long)mp * (5120L * 64) + (long)rr * 64 + cc] = f2bf(v);
      }
}

__device__ __forceinline__ void h1mean_item(int t, const unsigned short* h01,
                                            unsigned short* A3) {
  // t in [0, 32768): mp = t>>14, m = (t&16383)>>5, d8 = t&31
  int mp = t >> 14, t14 = t & 16383;
  int m = t14 >> 5, d8 = t14 & 31;
  const unsigned short* h1 = h01 + (long)mp * (5632L * 256) + 512 * 256;
  float s[8];
#pragma unroll
  for (int x = 0; x < 8; ++x) s[x] = 0.f;
#pragma unroll
  for (int ss = 0; ss < NS; ++ss) {
    uint4 v = *(const uint4*)(h1 + (long)(m * NS + ss) * 256 + d8 * 8);
    unsigned vals[4] = {v.x, v.y, v.z, v.w};
#pragma unroll
    for (int x = 0; x < 4; ++x) {
      s[x * 2]     += bf2f((unsigned short)(vals[x] & 0xFFFF));
      s[x * 2 + 1] += bf2f((unsigned short)(vals[x] >> 16));
    }
  }
  uint4 o;
  o.x = pk2(s[0] * 0.1f, s[1] * 0.1f);
  o.y = pk2(s[2] * 0.1f, s[3] * 0.1f);
  o.z = pk2(s[4] * 0.1f, s[5] * 0.1f);
  o.w = pk2(s[6] * 0.1f, s[7] * 0.1f);
  *(uint4*)(A3 + (long)mp * (512L * 576) + (long)m * 576 + 256 + d8 * 8) = o;
}

__global__ __launch_bounds__(256) void p3_k(
    const unsigned short* __restrict__ h01, const unsigned short* __restrict__ eg0,
    const unsigned short* __restrict__ wte, const float* __restrict__ bec,
    unsigned short* __restrict__ enew, unsigned short* __restrict__ A3) {
  __shared__ unsigned short sm[10240];
  int j = blockIdx.x;
  if (j < 160) edge_tile(j, h01, eg0, wte, bec, enew, sm, threadIdx.x);
  else h1mean_item((j - 160) * 256 + threadIdx.x, h01, A3);
}

// ===== GEMM3: osum = [A3 cols 0..511 | mean10(enew)] @ WT1[mp][1] ==========
// BM=32 BN=64 (128 tiles), 2-deep; e-mean on the fly in the A-stage (it>=16).
__device__ __forceinline__ uint4 g3A(const unsigned short* apt,
                                     const unsigned short* en, int gr, int q, int it) {
  if (it < 16) return *(const uint4*)(apt + it * 32);
  float s[8];
#pragma unroll
  for (int x = 0; x < 8; ++x) s[x] = 0.f;
#pragma unroll
  for (int ss = 0; ss < NS; ++ss) {
    uint4 v = *(const uint4*)(en + (long)(gr * NS + ss) * 64 + (it - 16) * 32 + q * 8);
    unsigned vals[4] = {v.x, v.y, v.z, v.w};
#pragma unroll
    for (int x = 0; x < 4; ++x) {
      s[x * 2]     += bf2f((unsigned short)(vals[x] & 0xFFFF));
      s[x * 2 + 1] += bf2f((unsigned short)(vals[x] >> 16));
    }
  }
  uint4 o;
  o.x = pk2(s[0] * 0.1f, s[1] * 0.1f);
  o.y = pk2(s[2] * 0.1f, s[3] * 0.1f);
  o.z = pk2(s[4] * 0.1f, s[5] * 0.1f);
  o.w = pk2(s[6] * 0.1f, s[7] * 0.1f);
  return o;
}

__global__ __launch_bounds__(256) void gemm3_k(
    const unsigned short* __restrict__ A3, const unsigned short* __restrict__ enew,
    const unsigned short* __restrict__ wt1, float* __restrict__ osum) {
  __shared__ unsigned short As[2][1280];
  __shared__ unsigned short Bs[2][2560];
  int tid = threadIdx.x, tile = blockIdx.x;
  int mp = tile & 1, t2 = tile >> 1;
  int n0 = (t2 & 3) * 64, m0 = (t2 >> 2) * 32;
  const unsigned short* Ap = A3 + (long)mp * (512L * 576) + (long)m0 * 576;
  const unsigned short* en = enew + (long)mp * (5120L * 64);
  const unsigned short* Bp = wt1 + (long)(mp * 2 + 1) * 147456 + (long)n0 * 576;

  int row = tid >> 2, q = tid & 3;   // row 0..63: B col; A uses row<32
  bool doA = (row < 32);
  int gr = m0 + row;
  const unsigned short* apt = Ap + (long)row * 576 + q * 8;
  const unsigned short* bpt = Bp + (long)row * 576 + q * 8;

  uint4 an, bn;
  {
    if (doA) {
      uint4 a = g3A(apt, en, gr, q, 0);
      *(uint4*)&As[0][row * 40 + q * 8] = a;
    }
    uint4 bv = *(const uint4*)bpt;
    *(uint4*)&Bs[0][row * 40 + q * 8] = bv;
  }
  if (doA) an = g3A(apt, en, gr, q, 1);
  bn = *(const uint4*)(bpt + 32);
  __syncthreads();

  f32x4 acc[2];
  acc[0] = (f32x4){0.f, 0.f, 0.f, 0.f};
  acc[1] = (f32x4){0.f, 0.f, 0.f, 0.f};

  int wave = tid >> 6, lane = tid & 63;
  int wm = wave >> 1, wn = wave & 1;
  int quad = lane >> 4, r16 = lane & 15;

  for (int it = 0; it < 18; ++it) {
    uint4 af_, bf_;
    if (it + 2 < 18) {
      if (doA) af_ = g3A(apt, en, gr, q, it + 2);
      bf_ = *(const uint4*)(bpt + (it + 2) * 32);
    }
    int c = it & 1;
    bf16x8 av = *(const bf16x8*)&As[c][(wm * 16 + r16) * 40 + quad * 8];
    bf16x8 bv[2];
#pragma unroll
    for (int j = 0; j < 2; ++j)
      bv[j] = *(const bf16x8*)&Bs[c][(wn * 32 + j * 16 + r16) * 40 + quad * 8];
#pragma unroll
    for (int j = 0; j < 2; ++j)
      acc[j] = __builtin_amdgcn_mfma_f32_16x16x32_bf16(av, bv[j], acc[j], 0, 0, 0);
    if (it + 1 < 18) {
      if (doA) *(uint4*)&As[c ^ 1][row * 40 + q * 8] = an;
      *(uint4*)&Bs[c ^ 1][row * 40 + q * 8] = bn;
      __syncthreads();
    }
    an = af_; bn = bf_;
  }
#pragma unroll
  for (int j = 0; j < 2; ++j)
#pragma unroll
    for (int r = 0; r < 4; ++r) {
      int rr = m0 + wm * 16 + quad * 4 + r;
      int cc = n0 + wn * 32 + j * 16 + r16;
      osum[(long)mp * 131072 + (long)rr * 256 + cc] = acc[j][r];
    }
}

// ---- finalize: out = normalize((o0+o1)/2) @ fc_w + fc_b; 4 rows/block ----
__global__ __launch_bounds__(256) void finalize_k(
    const float* __restrict__ osum, const float* __restrict__ fcw,
    const float* __restrict__ fcb, float* __restrict__ out) {
  int tid = threadIdx.x;
  int wave = tid >> 6, l = tid & 63;
  int b = blockIdx.x * 4 + wave;
  const float* o0 = osum;
  const float* o1 = osum + 131072;
  float v[4];
  float ss = 0.f;
#pragma unroll
  for (int k = 0; k < 4; ++k) {
    int j = l + 64 * k;
    v[k] = 0.5f * (o0[(long)b * 256 + j] + o1[(long)b * 256 + j]);
    ss += v[k] * v[k];
  }
#pragma unroll
  for (int off = 32; off > 0; off >>= 1) ss += __shfl_down(ss, off);
  ss = __shfl(ss, 0);
  float sc = 1.f / fmaxf(sqrtf(ss), 1e-12f);
  float p[8];
#pragma unroll
  for (int c = 0; c < 8; ++c) p[c] = 0.f;
#pragma unroll
  for (int k = 0; k < 4; ++k) {
    int j = l + 64 * k;
    float vh = v[k] * sc;
#pragma unroll
    for (int c = 0; c < 8; ++c) p[c] += vh * fcw[j * 8 + c];
  }
#pragma unroll
  for (int off = 32; off > 0; off >>= 1) {
#pragma unroll
    for (int c = 0; c < 8; ++c) p[c] += __shfl_down(p[c], off);
  }
  if (l == 0) {
#pragma unroll
    for (int c = 0; c < 8; ++c) out[b * 8 + c] = p[c] + fcb[c];
  }
}

extern "C" void kernel_launch(void* const* d_in, const int* in_sizes, int n_in,
                              void* d_out, int out_size, void* d_ws, size_t ws_size,
                              hipStream_t stream) {
  const int* ids = (const int*)d_in[0];
  const float* feats = (const float*)d_in[1];
  const int* n0i[2] = {(const int*)d_in[2], (const int*)d_in[4]};
  const int* n1i[2] = {(const int*)d_in[3], (const int*)d_in[5]};
  const int* e0i[2] = {(const int*)d_in[6], (const int*)d_in[8]};
  const int* e1i[2] = {(const int*)d_in[7], (const int*)d_in[9]};
  const float* emb[2] = {(const float*)d_in[10], (const float*)d_in[11]};
  const float* Wself = (const float*)d_in[12];
  const float* Wneigh = (const float*)d_in[13];
  const float* Wedg = (const float*)d_in[14];
  const float* Wec = (const float*)d_in[15];
  const float* bec = (const float*)d_in[16];
  const float* fcw = (const float*)d_in[17];
  const float* fcb = (const float*)d_in[18];
  float* out = (float*)d_out;

  // ---- workspace ----
  float* osum = (float*)d_ws;                               // [2][512][256] f32
  unsigned short* A1b  = (unsigned short*)(osum + 262144);  // [2][5632][576]
  unsigned short* eg0  = A1b + 6488064;                     // [2][5120][64]
  unsigned short* h01  = eg0 + 655360;                      // [2][5632][256]
  unsigned short* enew = h01 + 2883584;                     // [2][5120][64]
  unsigned short* wt1  = enew + 655360;                     // [4][256][576]
  unsigned short* wte  = wt1 + 589824;                      // [2][64][576]
  unsigned short* A3   = wte + 73728;                       // [2][512][576]

  // ---- gather jobs (dual jobs fuse direct-copy + mean over same rows) ----
  GJobs gj; int blk = 0, nj = 0;
  {
    auto add = [&](const float* table, const int* idx, unsigned short* o,
                   int M, int D4, int ns, int ostride, float inv,
                   unsigned short* o2, int ostride2) {
      gj.j[nj] = {table, idx, o, o2, M, D4, ns, ostride, ostride2, blk, inv};
      blk += (M * D4) / 256; ++nj;
    };
    for (int mp = 0; mp < 2; ++mp) {
      unsigned short* Am = A1b + (size_t)mp * 5632 * 576;
      add(feats, ids, Am, 512, 64, 1, 576, 1.0f, nullptr, 0);
      add(feats, n0i[mp], Am + 256, 512, 64, NS, 576, 0.1f, Am + 512 * 576, 576);
      add(feats, n1i[mp], Am + 512 * 576 + 256, 5120, 64, NS, 576, 0.1f, nullptr, 0);
      add(emb[mp], e0i[mp], Am + 512, 512, 16, NS, 576, 0.1f,
          eg0 + (size_t)mp * 327680, 64);
      add(emb[mp], e1i[mp], Am + 512 * 576 + 512, 5120, 16, NS, 576, 0.1f, nullptr, 0);
    }
  }

  // 1) prep: weight pack (transpose tiles) + gathers
  gprep_k<<<dim3(PACKT + blk), dim3(256), 0, stream>>>(
      gj, nj, Wself, Wneigh, Wedg, Wec, wt1, wte);

  // 2) layer-0 agg (704 tiles); tees h0 rows into A3
  gemm1_k<<<dim3(704), dim3(256), 0, stream>>>(A1b, wt1, h01, A3);

  // 3) edge GEMM (160 tiles) || h1-means (128 blocks)
  p3_k<<<dim3(288), dim3(256), 0, stream>>>(h01, eg0, wte, bec, enew, A3);

  // 4) layer-1 agg with on-the-fly e-means (128 tiles, BM=32)
  gemm3_k<<<dim3(128), dim3(256), 0, stream>>>(A3, enew, wt1, osum);

  // 5) metapath mean + L2 normalize + FC
  finalize_k<<<dim3(128), dim3(256), 0, stream>>>(osum, fcw, fcb, out);
}